// Round 1
// baseline (255.049 us; speedup 1.0000x reference)
//
#include <hip/hip_runtime.h>
#include <cstdint>

#define DEV __device__ __forceinline__

typedef __bf16 bf16x4 __attribute__((ext_vector_type(4)));
typedef __bf16 bf16x8 __attribute__((ext_vector_type(8)));
typedef float  floatx4 __attribute__((ext_vector_type(4)));

constexpr int BB = 8, NSEQ = 1024, DMODEL = 768, NH = 12, HD = 64;
constexpr int MTOK = BB * NSEQ;   // 8192 tokens
constexpr int NQKV = 3 * DMODEL;  // 2304

DEV void async_copy16(void* lds, const void* g) {
    // global -> LDS direct copy, 16B/lane. LDS dest must be wave-base + lane*16.
    __builtin_amdgcn_global_load_lds(
        (__attribute__((address_space(1))) void*)(const_cast<void*>(g)),
        (__attribute__((address_space(3))) void*)lds,
        16, 0, 0);
}

DEV floatx4 mfma16(bf16x8 a, bf16x8 b, floatx4 c) {
    return __builtin_amdgcn_mfma_f32_16x16x32_bf16(a, b, c, 0, 0, 0);
}

// ---------------- x fp32 -> bf16 ----------------
__global__ __launch_bounds__(256) void k_convert_x(const float* __restrict__ x,
                                                   __bf16* __restrict__ xb) {
    int i = (blockIdx.x * 256 + threadIdx.x) * 4;  // grid sized exactly
    float4 v = *(const float4*)(x + i);
    bf16x4 o;
    o[0] = (__bf16)v.x; o[1] = (__bf16)v.y; o[2] = (__bf16)v.z; o[3] = (__bf16)v.w;
    *(bf16x4*)(xb + i) = o;
}

// ---------------- bias concat (q|k|v) fp32 ----------------
__global__ __launch_bounds__(256) void k_bias(const float* __restrict__ bq,
                                              const float* __restrict__ bk,
                                              const float* __restrict__ bv,
                                              float* __restrict__ out) {
    int i = blockIdx.x * 256 + threadIdx.x;  // grid = 9 -> 2304 exact
    if (i < 768) out[i] = bq[i];
    else if (i < 1536) out[i] = bk[i - 768];
    else if (i < 2304) out[i] = bv[i - 1536];
}

// ---------------- W [K,N] fp32 -> Wt [N,K] bf16 (z: 0=q 1=k 2=v 3=o) ----------------
__global__ __launch_bounds__(256) void k_transpose_w(const float* __restrict__ Wq,
                                                     const float* __restrict__ Wk,
                                                     const float* __restrict__ Wv,
                                                     const float* __restrict__ Wo,
                                                     __bf16* __restrict__ wtqkv,
                                                     __bf16* __restrict__ wto) {
    __shared__ float tile[32][33];
    int z = blockIdx.z;
    const float* W = (z == 0) ? Wq : (z == 1) ? Wk : (z == 2) ? Wv : Wo;
    int k0 = blockIdx.x * 32, n0 = blockIdx.y * 32;
    int tx = threadIdx.x & 31, ty = threadIdx.x >> 5;
#pragma unroll
    for (int p = 0; p < 4; p++)
        tile[ty + 8 * p][tx] = W[(size_t)(k0 + ty + 8 * p) * 768 + n0 + tx];
    __syncthreads();
    __bf16* out = (z < 3) ? (wtqkv + (size_t)z * 768 * 768) : wto;
#pragma unroll
    for (int p = 0; p < 4; p++)
        out[(size_t)(n0 + ty + 8 * p) * 768 + k0 + tx] = (__bf16)tile[tx][ty + 8 * p];
}

// ---------------- GEMM: C[M,Nn] = A[M,768] @ Bt[Nn,768]^T + bias ----------------
// BM=BN=128, BK=64, 4 waves each 64x64 (4x4 acc of 16x16x32 MFMA).
// LDS rows are 8 chunks of 16B; chunk XOR-swizzled with (row&7) -> 2-way-free ds_read_b128.
template <typename OutT>
__global__ __launch_bounds__(256) void k_gemm(const __bf16* __restrict__ A,
                                              const __bf16* __restrict__ Bt,
                                              const float* __restrict__ bias,
                                              OutT* __restrict__ C, int Nn) {
    __shared__ __align__(16) __bf16 As[128 * 64];
    __shared__ __align__(16) __bf16 Bs[128 * 64];
    int t = threadIdx.x, lane = t & 63, w = t >> 6;
    int quad = lane >> 4, n16 = lane & 15;
    int wm = w & 1, wn = w >> 1;
    int m0 = blockIdx.x * 128, n0 = blockIdx.y * 128;
    floatx4 acc[4][4] = {};

    for (int k0 = 0; k0 < 768; k0 += 64) {
        __syncthreads();
#pragma unroll
        for (int i = 0; i < 4; i++) {  // stage A tile 128x64 (16KB)
            int off = t + i * 256;
            int row = off >> 3, pc = off & 7;
            int c = pc ^ (row & 7);
            async_copy16(&As[row * 64 + pc * 8],
                         &A[(size_t)(m0 + row) * 768 + k0 + c * 8]);
        }
#pragma unroll
        for (int i = 0; i < 4; i++) {  // stage B tile 128x64
            int off = t + i * 256;
            int row = off >> 3, pc = off & 7;
            int c = pc ^ (row & 7);
            async_copy16(&Bs[row * 64 + pc * 8],
                         &Bt[(size_t)(n0 + row) * 768 + k0 + c * 8]);
        }
        __builtin_amdgcn_s_waitcnt(0);  // drain global_load_lds before barrier
        __syncthreads();
#pragma unroll
        for (int kfi = 0; kfi < 2; kfi++) {
            bf16x8 a[4], bfr[4];
#pragma unroll
            for (int rt = 0; rt < 4; rt++) {
                int row = wm * 64 + rt * 16 + n16;
                a[rt] = *(const bf16x8*)&As[row * 64 + ((quad + 4 * kfi) ^ (row & 7)) * 8];
            }
#pragma unroll
            for (int ct = 0; ct < 4; ct++) {
                int row = wn * 64 + ct * 16 + n16;
                bfr[ct] = *(const bf16x8*)&Bs[row * 64 + ((quad + 4 * kfi) ^ (row & 7)) * 8];
            }
#pragma unroll
            for (int rt = 0; rt < 4; rt++)
#pragma unroll
                for (int ct = 0; ct < 4; ct++)
                    acc[rt][ct] = mfma16(a[rt], bfr[ct], acc[rt][ct]);
        }
    }
    // epilogue: C/D layout col=lane&15, row=quad*4+reg
#pragma unroll
    for (int ct = 0; ct < 4; ct++) {
        int col = n0 + wn * 64 + ct * 16 + n16;
        float bs = bias[col];
#pragma unroll
        for (int rt = 0; rt < 4; rt++) {
#pragma unroll
            for (int r = 0; r < 4; r++) {
                int row = m0 + wm * 64 + rt * 16 + quad * 4 + r;
                C[(size_t)row * Nn + col] = (OutT)(acc[rt][ct][r] + bs);
            }
        }
    }
}

// ---------------- V region of qkv -> vt[b,h,hd,tok] ----------------
__global__ __launch_bounds__(256) void k_transpose_v(const __bf16* __restrict__ qkv,
                                                     __bf16* __restrict__ vt) {
    __shared__ __align__(16) __bf16 tile[64 * 72];  // [hd][tok], stride 72
    int t = threadIdx.x;
    int tok0 = blockIdx.x * 64, h = blockIdx.y, b = blockIdx.z;
#pragma unroll
    for (int p = 0; p < 2; p++) {
        int tokl = p * 32 + (t >> 3);
        int hd0 = (t & 7) * 8;
        bf16x8 v = *(const bf16x8*)&qkv[(size_t)(b * NSEQ + tok0 + tokl) * NQKV + 1536 + h * 64 + hd0];
#pragma unroll
        for (int j = 0; j < 8; j++) tile[(hd0 + j) * 72 + tokl] = v[j];
    }
    __syncthreads();
    int hd = t >> 2, ch = t & 3;
    const __bf16* src = &tile[hd * 72 + ch * 16];
    __bf16* dst = vt + (size_t)((b * NH + h) * 64 + hd) * NSEQ + tok0 + ch * 16;
    *(bf16x8*)dst = *(const bf16x8*)src;
    *(bf16x8*)(dst + 8) = *(const bf16x8*)(src + 8);
}

// ---------------- flash attention with quiet softmax ----------------
// block = (q-tile 64, head, batch); 4 waves x 16 q-rows each; K/V tiles 64 keys.
__global__ __launch_bounds__(256) void k_attn(const __bf16* __restrict__ qkv,
                                              const __bf16* __restrict__ vt,
                                              __bf16* __restrict__ ctx) {
    __shared__ __align__(16) __bf16 Ks[64 * 64];      // [key][hd], chunk-swizzled
    __shared__ __align__(16) __bf16 Vs[64 * 64];      // [hd][key], chunk-swizzled
    __shared__ __align__(16) __bf16 Ps[4][16 * 72];   // per-wave P / out staging
    int t = threadIdx.x, lane = t & 63, w = t >> 6;
    int quad = lane >> 4, n16 = lane & 15;
    int q0 = blockIdx.x * 64, h = blockIdx.y, b = blockIdx.z;

    // Q fragments for this wave's 16 rows (held in regs across the K loop)
    bf16x8 aq[2];
    {
        const __bf16* qp = qkv + (size_t)(b * NSEQ + q0 + w * 16 + n16) * NQKV + h * 64 + quad * 8;
        aq[0] = *(const bf16x8*)qp;
        aq[1] = *(const bf16x8*)(qp + 32);
    }
    floatx4 acc_o[4] = {};
    float mrun[4], lrun[4];
#pragma unroll
    for (int r = 0; r < 4; r++) { mrun[r] = -1e30f; lrun[r] = 0.f; }

    for (int kt = 0; kt < 16; kt++) {
        __syncthreads();
#pragma unroll
        for (int ii = 0; ii < 2; ii++) {  // stage K (8KB) and V^T (8KB)
            int rowl = w * 16 + ii * 8 + (lane >> 3);
            int pc = lane & 7;
            int c = pc ^ (rowl & 7);
            async_copy16(&Ks[rowl * 64 + pc * 8],
                         &qkv[(size_t)(b * NSEQ + kt * 64 + rowl) * NQKV + 768 + h * 64 + c * 8]);
            async_copy16(&Vs[rowl * 64 + pc * 8],
                         &vt[(size_t)((b * NH + h) * 64 + rowl) * NSEQ + kt * 64 + c * 8]);
        }
        __builtin_amdgcn_s_waitcnt(0);
        __syncthreads();

        // S = Q K^T  (16 q-rows x 64 keys per wave)
        floatx4 s[4] = {};
#pragma unroll
        for (int ng = 0; ng < 4; ng++) {
            int krow = ng * 16 + n16;
#pragma unroll
            for (int kfi = 0; kfi < 2; kfi++) {
                bf16x8 bk = *(const bf16x8*)&Ks[krow * 64 + ((quad + 4 * kfi) ^ (krow & 7)) * 8];
                s[ng] = mfma16(aq[kfi], bk, s[ng]);
            }
        }
#pragma unroll
        for (int ng = 0; ng < 4; ng++) s[ng] *= 0.125f;  // 1/sqrt(64)

        // online quiet softmax; row = quad*4+r, replicated across 16 lanes of quad
        float alpha[4];
#pragma unroll
        for (int r = 0; r < 4; r++) {
            float tm = fmaxf(fmaxf(s[0][r], s[1][r]), fmaxf(s[2][r], s[3][r]));
            tm = fmaxf(tm, __shfl_xor(tm, 1));
            tm = fmaxf(tm, __shfl_xor(tm, 2));
            tm = fmaxf(tm, __shfl_xor(tm, 4));
            tm = fmaxf(tm, __shfl_xor(tm, 8));
            float mnew = fmaxf(mrun[r], tm);
            alpha[r] = __expf(mrun[r] - mnew);
            mrun[r] = mnew;
            float rs = 0.f;
#pragma unroll
            for (int ng = 0; ng < 4; ng++) {
                float p = __expf(s[ng][r] - mnew);
                s[ng][r] = p;
                rs += p;
            }
            rs += __shfl_xor(rs, 1);
            rs += __shfl_xor(rs, 2);
            rs += __shfl_xor(rs, 4);
            rs += __shfl_xor(rs, 8);
            lrun[r] = lrun[r] * alpha[r] + rs;
        }

        // P: C-layout -> A-layout via per-wave LDS (stride 72 kills bank conflicts)
#pragma unroll
        for (int ng = 0; ng < 4; ng++)
#pragma unroll
            for (int r = 0; r < 4; r++)
                Ps[w][(quad * 4 + r) * 72 + ng * 16 + n16] = (__bf16)s[ng][r];
        __builtin_amdgcn_s_waitcnt(0);
        bf16x8 ap[2];
        ap[0] = *(const bf16x8*)&Ps[w][n16 * 72 + quad * 8];
        ap[1] = *(const bf16x8*)&Ps[w][n16 * 72 + 32 + quad * 8];

#pragma unroll
        for (int hg = 0; hg < 4; hg++) {
            floatx4 o = acc_o[hg];
#pragma unroll
            for (int r = 0; r < 4; r++) o[r] *= alpha[r];
            acc_o[hg] = o;
        }
#pragma unroll
        for (int hg = 0; hg < 4; hg++) {
            int vrow = hg * 16 + n16;
#pragma unroll
            for (int kfi = 0; kfi < 2; kfi++) {
                bf16x8 bv = *(const bf16x8*)&Vs[vrow * 64 + ((quad + 4 * kfi) ^ (vrow & 7)) * 8];
                acc_o[hg] = mfma16(ap[kfi], bv, acc_o[hg]);
            }
        }
    }

    // finalize: quiet denom = 1 + sum(e^{s-M}); stage to LDS, store coalesced
    float inv[4];
#pragma unroll
    for (int r = 0; r < 4; r++) inv[r] = 1.f / (1.f + lrun[r]);
#pragma unroll
    for (int hg = 0; hg < 4; hg++)
#pragma unroll
        for (int r = 0; r < 4; r++)
            Ps[w][(quad * 4 + r) * 72 + hg * 16 + n16] = (__bf16)(acc_o[hg][r] * inv[r]);
    __builtin_amdgcn_s_waitcnt(0);
    int row = lane >> 2, ch = lane & 3;
    const __bf16* src = &Ps[w][row * 72 + ch * 16];
    __bf16* dst = ctx + (size_t)(b * NSEQ + q0 + w * 16 + row) * DMODEL + h * 64 + ch * 16;
    *(bf16x8*)dst = *(const bf16x8*)src;
    *(bf16x8*)(dst + 8) = *(const bf16x8*)(src + 8);
}

extern "C" void kernel_launch(void* const* d_in, const int* in_sizes, int n_in,
                              void* d_out, int out_size, void* d_ws, size_t ws_size,
                              hipStream_t stream) {
    (void)in_sizes; (void)n_in; (void)out_size;
    const float* x  = (const float*)d_in[0];
    const float* Wq = (const float*)d_in[1];
    const float* bq = (const float*)d_in[2];
    const float* Wk = (const float*)d_in[3];
    const float* bk = (const float*)d_in[4];
    const float* Wv = (const float*)d_in[5];
    const float* bv = (const float*)d_in[6];
    const float* Wo = (const float*)d_in[7];
    const float* bo = (const float*)d_in[8];
    float* out = (float*)d_out;

    char* ws = (char*)d_ws;
    size_t off = 0;
    auto alloc = [&](size_t bytes) {
        void* p = ws + off;
        off += (bytes + 255) & ~(size_t)255;
        return p;
    };
    __bf16* xb    = (__bf16*)alloc((size_t)MTOK * DMODEL * 2);   // 12.6 MB (reused as ctx)
    __bf16* wtqkv = (__bf16*)alloc((size_t)NQKV * DMODEL * 2);   // 3.5 MB
    __bf16* wto   = (__bf16*)alloc((size_t)DMODEL * DMODEL * 2); // 1.2 MB
    float*  bqkv  = (float*)alloc((size_t)NQKV * 4);
    __bf16* qkvb  = (__bf16*)alloc((size_t)MTOK * NQKV * 2);     // 37.7 MB
    __bf16* vtb   = (__bf16*)alloc((size_t)BB * NH * HD * NSEQ * 2); // 12.6 MB
    if (off > ws_size) return;  // workspace too small -> visible failure
    __bf16* ctx = xb;  // xb dead after QKV GEMM

    k_convert_x<<<dim3(6144), dim3(256), 0, stream>>>(x, xb);
    k_bias<<<dim3(9), dim3(256), 0, stream>>>(bq, bk, bv, bqkv);
    k_transpose_w<<<dim3(24, 24, 4), dim3(256), 0, stream>>>(Wq, Wk, Wv, Wo, wtqkv, wto);
    k_gemm<__bf16><<<dim3(64, 18), dim3(256), 0, stream>>>(xb, wtqkv, bqkv, qkvb, NQKV);
    k_transpose_v<<<dim3(16, 12, 8), dim3(256), 0, stream>>>(qkvb, vtb);
    k_attn<<<dim3(16, 12, 8), dim3(256), 0, stream>>>(qkvb, vtb, ctx);
    k_gemm<float><<<dim3(64, 6), dim3(256), 0, stream>>>(ctx, wto, bo, out, DMODEL);
}

// Round 2
// 231.647 us; speedup vs baseline: 1.1010x; 1.1010x over previous
//
#include <hip/hip_runtime.h>
#include <cstdint>

#define DEV __device__ __forceinline__

typedef __bf16 bf16x4 __attribute__((ext_vector_type(4)));
typedef __bf16 bf16x8 __attribute__((ext_vector_type(8)));
typedef float  floatx4 __attribute__((ext_vector_type(4)));

constexpr int BB = 8, NSEQ = 1024, DMODEL = 768, NH = 12, HD = 64;
constexpr int MTOK = BB * NSEQ;   // 8192 tokens
constexpr int NQKV = 3 * DMODEL;  // 2304

DEV void async_copy16(void* lds, const void* g) {
    // global -> LDS direct copy, 16B/lane. LDS dest must be wave-base + lane*16.
    __builtin_amdgcn_global_load_lds(
        (__attribute__((address_space(1))) void*)(const_cast<void*>(g)),
        (__attribute__((address_space(3))) void*)lds,
        16, 0, 0);
}

DEV floatx4 mfma16(bf16x8 a, bf16x8 b, floatx4 c) {
    return __builtin_amdgcn_mfma_f32_16x16x32_bf16(a, b, c, 0, 0, 0);
}

// ---------------- x fp32 -> bf16 ----------------
__global__ __launch_bounds__(256) void k_convert_x(const float* __restrict__ x,
                                                   __bf16* __restrict__ xb) {
    int i = (blockIdx.x * 256 + threadIdx.x) * 4;  // grid sized exactly
    float4 v = *(const float4*)(x + i);
    bf16x4 o;
    o[0] = (__bf16)v.x; o[1] = (__bf16)v.y; o[2] = (__bf16)v.z; o[3] = (__bf16)v.w;
    *(bf16x4*)(xb + i) = o;
}

// ---------------- bias concat (q|k|v) fp32 ----------------
__global__ __launch_bounds__(256) void k_bias(const float* __restrict__ bq,
                                              const float* __restrict__ bk,
                                              const float* __restrict__ bv,
                                              float* __restrict__ out) {
    int i = blockIdx.x * 256 + threadIdx.x;  // grid = 9 -> 2304 exact
    if (i < 768) out[i] = bq[i];
    else if (i < 1536) out[i] = bk[i - 768];
    else if (i < 2304) out[i] = bv[i - 1536];
}

// ---------------- W [K,N] fp32 -> Wt [N,K] bf16 (z: 0=q 1=k 2=v 3=o) ----------------
__global__ __launch_bounds__(256) void k_transpose_w(const float* __restrict__ Wq,
                                                     const float* __restrict__ Wk,
                                                     const float* __restrict__ Wv,
                                                     const float* __restrict__ Wo,
                                                     __bf16* __restrict__ wtqkv,
                                                     __bf16* __restrict__ wto) {
    __shared__ float tile[32][33];
    int z = blockIdx.z;
    const float* W = (z == 0) ? Wq : (z == 1) ? Wk : (z == 2) ? Wv : Wo;
    int k0 = blockIdx.x * 32, n0 = blockIdx.y * 32;
    int tx = threadIdx.x & 31, ty = threadIdx.x >> 5;
#pragma unroll
    for (int p = 0; p < 4; p++)
        tile[ty + 8 * p][tx] = W[(size_t)(k0 + ty + 8 * p) * 768 + n0 + tx];
    __syncthreads();
    __bf16* out = (z < 3) ? (wtqkv + (size_t)z * 768 * 768) : wto;
#pragma unroll
    for (int p = 0; p < 4; p++)
        out[(size_t)(n0 + ty + 8 * p) * 768 + k0 + tx] = (__bf16)tile[tx][ty + 8 * p];
}

// ---------------- GEMM: C[M,Nn] = A[M,768] @ Bt[Nn,768]^T + bias ----------------
// BM=BN=128, BK=64, 4 waves each 64x64 (4x4 acc of 16x16x32 MFMA).
// LDS rows are 8 chunks of 16B; chunk XOR-swizzled with (row&7) -> 2-way-free ds_read_b128.
template <typename OutT>
__global__ __launch_bounds__(256) void k_gemm(const __bf16* __restrict__ A,
                                              const __bf16* __restrict__ Bt,
                                              const float* __restrict__ bias,
                                              OutT* __restrict__ C, int Nn) {
    __shared__ __align__(16) __bf16 As[128 * 64];
    __shared__ __align__(16) __bf16 Bs[128 * 64];
    int t = threadIdx.x, lane = t & 63, w = t >> 6;
    int quad = lane >> 4, n16 = lane & 15;
    int wm = w & 1, wn = w >> 1;
    int m0 = blockIdx.x * 128, n0 = blockIdx.y * 128;
    floatx4 acc[4][4] = {};

    for (int k0 = 0; k0 < 768; k0 += 64) {
        __syncthreads();
#pragma unroll
        for (int i = 0; i < 4; i++) {  // stage A tile 128x64 (16KB)
            int off = t + i * 256;
            int row = off >> 3, pc = off & 7;
            int c = pc ^ (row & 7);
            async_copy16(&As[row * 64 + pc * 8],
                         &A[(size_t)(m0 + row) * 768 + k0 + c * 8]);
        }
#pragma unroll
        for (int i = 0; i < 4; i++) {  // stage B tile 128x64
            int off = t + i * 256;
            int row = off >> 3, pc = off & 7;
            int c = pc ^ (row & 7);
            async_copy16(&Bs[row * 64 + pc * 8],
                         &Bt[(size_t)(n0 + row) * 768 + k0 + c * 8]);
        }
        __builtin_amdgcn_s_waitcnt(0);  // drain global_load_lds before barrier
        __syncthreads();
#pragma unroll
        for (int kfi = 0; kfi < 2; kfi++) {
            bf16x8 a[4], bfr[4];
#pragma unroll
            for (int rt = 0; rt < 4; rt++) {
                int row = wm * 64 + rt * 16 + n16;
                a[rt] = *(const bf16x8*)&As[row * 64 + ((quad + 4 * kfi) ^ (row & 7)) * 8];
            }
#pragma unroll
            for (int ct = 0; ct < 4; ct++) {
                int row = wn * 64 + ct * 16 + n16;
                bfr[ct] = *(const bf16x8*)&Bs[row * 64 + ((quad + 4 * kfi) ^ (row & 7)) * 8];
            }
#pragma unroll
            for (int rt = 0; rt < 4; rt++)
#pragma unroll
                for (int ct = 0; ct < 4; ct++)
                    acc[rt][ct] = mfma16(a[rt], bfr[ct], acc[rt][ct]);
        }
    }
    // epilogue: C/D layout col=lane&15, row=quad*4+reg
#pragma unroll
    for (int ct = 0; ct < 4; ct++) {
        int col = n0 + wn * 64 + ct * 16 + n16;
        float bs = bias[col];
#pragma unroll
        for (int rt = 0; rt < 4; rt++) {
#pragma unroll
            for (int r = 0; r < 4; r++) {
                int row = m0 + wm * 64 + rt * 16 + quad * 4 + r;
                C[(size_t)row * Nn + col] = (OutT)(acc[rt][ct][r] + bs);
            }
        }
    }
}

// ---------------- V region of qkv -> vt[b,h,hd,tok] ----------------
__global__ __launch_bounds__(256) void k_transpose_v(const __bf16* __restrict__ qkv,
                                                     __bf16* __restrict__ vt) {
    __shared__ __align__(16) __bf16 tile[64 * 72];  // [hd][tok], stride 72
    int t = threadIdx.x;
    int tok0 = blockIdx.x * 64, h = blockIdx.y, b = blockIdx.z;
#pragma unroll
    for (int p = 0; p < 2; p++) {
        int tokl = p * 32 + (t >> 3);
        int hd0 = (t & 7) * 8;
        bf16x8 v = *(const bf16x8*)&qkv[(size_t)(b * NSEQ + tok0 + tokl) * NQKV + 1536 + h * 64 + hd0];
#pragma unroll
        for (int j = 0; j < 8; j++) tile[(hd0 + j) * 72 + tokl] = v[j];
    }
    __syncthreads();
    int hd = t >> 2, ch = t & 3;
    const __bf16* src = &tile[hd * 72 + ch * 16];
    __bf16* dst = vt + (size_t)((b * NH + h) * 64 + hd) * NSEQ + tok0 + ch * 16;
    *(bf16x8*)dst = *(const bf16x8*)src;
    *(bf16x8*)(dst + 8) = *(const bf16x8*)(src + 8);
}

// ---------------- flash attention, transposed dataflow ----------------
// S^T = K Q^T  (C-layout col = q-row -> per-lane softmax state)
// O^T = V^T P^T (C-layout col = q-row -> scalar alpha rescale)
// block = (q-tile 64, head, batch); 4 waves x 16 q-rows each; K/V tiles 64 keys.
__global__ __launch_bounds__(256) void k_attn(const __bf16* __restrict__ qkv,
                                              const __bf16* __restrict__ vt,
                                              __bf16* __restrict__ ctx) {
    __shared__ __align__(16) __bf16 Ks[64 * 64];      // [key][hd], chunk-swizzled
    __shared__ __align__(16) __bf16 Vs[64 * 64];      // [hd][key], chunk-swizzled
    __shared__ __align__(16) __bf16 Ps[4][16 * 72];   // per-wave [qrow][key|hd], stride 72
    int t = threadIdx.x, lane = t & 63, w = t >> 6;
    int quad = lane >> 4, n16 = lane & 15;
    int q0 = blockIdx.x * 64, h = blockIdx.y, b = blockIdx.z;

    // Q fragment (B-operand): n = qrow = n16, k = quad*8+j (+32 per kfi)
    bf16x8 qf[2];
    {
        const __bf16* qp = qkv + (size_t)(b * NSEQ + q0 + w * 16 + n16) * NQKV + h * 64 + quad * 8;
        qf[0] = *(const bf16x8*)qp;
        qf[1] = *(const bf16x8*)(qp + 32);
    }
    // staging induction pointers: each wave stages rows w*16+ii*8+(lane>>3)
    int srow0 = w * 16 + (lane >> 3);
    int pc = lane & 7;
    const __bf16* kg[2];
    const __bf16* vg[2];
    __bf16* kl[2];
    __bf16* vl[2];
#pragma unroll
    for (int ii = 0; ii < 2; ii++) {
        int rowl = srow0 + ii * 8;
        int c = pc ^ (rowl & 7);
        kg[ii] = qkv + (size_t)(b * NSEQ + rowl) * NQKV + 768 + h * 64 + c * 8;
        vg[ii] = vt + (size_t)((b * NH + h) * 64 + rowl) * NSEQ + c * 8;
        kl[ii] = &Ks[rowl * 64 + pc * 8];
        vl[ii] = &Vs[rowl * 64 + pc * 8];
    }

    floatx4 acc_o[4] = {};
    float mrun = -1e30f, lrun = 0.f;
    const float cs = 0.125f * 1.44269504089f;  // (1/sqrt(64)) * log2(e)

    for (int kt = 0; kt < 16; kt++) {
        __syncthreads();
#pragma unroll
        for (int ii = 0; ii < 2; ii++) {
            async_copy16(kl[ii], kg[ii]);
            async_copy16(vl[ii], vg[ii]);
            kg[ii] += 64 * NQKV;
            vg[ii] += 64;
        }
        __builtin_amdgcn_s_waitcnt(0);  // drain global_load_lds before barrier
        __syncthreads();

        // S^T tile: A = K (m=key), B = Q (n=qrow). lane holds keys ng*16+quad*4+r, qrow n16.
        floatx4 s[4] = {};
#pragma unroll
        for (int ng = 0; ng < 4; ng++) {
            int krow = ng * 16 + n16;
#pragma unroll
            for (int kfi = 0; kfi < 2; kfi++) {
                bf16x8 kf = *(const bf16x8*)&Ks[krow * 64 + ((quad + 4 * kfi) ^ (krow & 7)) * 8];
                s[ng] = mfma16(kf, qf[kfi], s[ng]);
            }
        }

        // online quiet softmax in base-2, one q-row per lane (replicated x4 across quads)
        float tm = fmaxf(fmaxf(fmaxf(s[0][0], s[0][1]), fmaxf(s[0][2], s[0][3])),
                         fmaxf(fmaxf(s[1][0], s[1][1]), fmaxf(s[1][2], s[1][3])));
        tm = fmaxf(tm, fmaxf(fmaxf(fmaxf(s[2][0], s[2][1]), fmaxf(s[2][2], s[2][3])),
                             fmaxf(fmaxf(s[3][0], s[3][1]), fmaxf(s[3][2], s[3][3]))));
        tm = fmaxf(tm, __shfl_xor(tm, 16));
        tm = fmaxf(tm, __shfl_xor(tm, 32));
        float mnew = fmaxf(mrun, tm * cs);
        float alpha = exp2f(mrun - mnew);
        mrun = mnew;

        float rs = 0.f;
        bf16x4 pk[4];
#pragma unroll
        for (int ng = 0; ng < 4; ng++) {
#pragma unroll
            for (int r = 0; r < 4; r++) {
                float p = exp2f(fmaf(s[ng][r], cs, -mnew));
                rs += p;
                pk[ng][r] = (__bf16)p;
            }
        }
        rs += __shfl_xor(rs, 16);
        rs += __shfl_xor(rs, 32);
        lrun = lrun * alpha + rs;

        // P[qrow][key]: lane writes 4 contiguous keys per tile -> ds_write_b64
#pragma unroll
        for (int ng = 0; ng < 4; ng++)
            *(bf16x4*)&Ps[w][n16 * 72 + ng * 16 + quad * 4] = pk[ng];
        asm volatile("s_waitcnt lgkmcnt(0)" ::: "memory");  // intra-wave LDS drain only
        bf16x8 ap[2];
        ap[0] = *(const bf16x8*)&Ps[w][n16 * 72 + quad * 8];
        ap[1] = *(const bf16x8*)&Ps[w][n16 * 72 + 32 + quad * 8];

        // O^T += V^T P^T: A = V^T (m=hd), B = P^T (n=qrow). alpha is lane-uniform.
#pragma unroll
        for (int hg = 0; hg < 4; hg++) {
            floatx4 o = acc_o[hg];
#pragma unroll
            for (int r = 0; r < 4; r++) o[r] *= alpha;
            int vrow = hg * 16 + n16;
#pragma unroll
            for (int kfi = 0; kfi < 2; kfi++) {
                bf16x8 vf = *(const bf16x8*)&Vs[vrow * 64 + ((quad + 4 * kfi) ^ (vrow & 7)) * 8];
                o = mfma16(vf, ap[kfi], o);
            }
            acc_o[hg] = o;
        }
    }

    // finalize: quiet denom = 1 + l; O^T[hd][qrow] -> Ps[qrow][hd] (b64), store coalesced
    float inv = 1.f / (1.f + lrun);
#pragma unroll
    for (int hg = 0; hg < 4; hg++) {
        bf16x4 ok;
#pragma unroll
        for (int r = 0; r < 4; r++) ok[r] = (__bf16)(acc_o[hg][r] * inv);
        *(bf16x4*)&Ps[w][n16 * 72 + hg * 16 + quad * 4] = ok;
    }
    asm volatile("s_waitcnt lgkmcnt(0)" ::: "memory");
    int row = lane >> 2, ch = lane & 3;
    const __bf16* src = &Ps[w][row * 72 + ch * 16];
    __bf16* dst = ctx + (size_t)(b * NSEQ + q0 + w * 16 + row) * DMODEL + h * 64 + ch * 16;
    *(bf16x8*)dst = *(const bf16x8*)src;
    *(bf16x8*)(dst + 8) = *(const bf16x8*)(src + 8);
}

extern "C" void kernel_launch(void* const* d_in, const int* in_sizes, int n_in,
                              void* d_out, int out_size, void* d_ws, size_t ws_size,
                              hipStream_t stream) {
    (void)in_sizes; (void)n_in; (void)out_size;
    const float* x  = (const float*)d_in[0];
    const float* Wq = (const float*)d_in[1];
    const float* bq = (const float*)d_in[2];
    const float* Wk = (const float*)d_in[3];
    const float* bk = (const float*)d_in[4];
    const float* Wv = (const float*)d_in[5];
    const float* bv = (const float*)d_in[6];
    const float* Wo = (const float*)d_in[7];
    const float* bo = (const float*)d_in[8];
    float* out = (float*)d_out;

    char* ws = (char*)d_ws;
    size_t off = 0;
    auto alloc = [&](size_t bytes) {
        void* p = ws + off;
        off += (bytes + 255) & ~(size_t)255;
        return p;
    };
    __bf16* xb    = (__bf16*)alloc((size_t)MTOK * DMODEL * 2);   // 12.6 MB (reused as ctx)
    __bf16* wtqkv = (__bf16*)alloc((size_t)NQKV * DMODEL * 2);   // 3.5 MB
    __bf16* wto   = (__bf16*)alloc((size_t)DMODEL * DMODEL * 2); // 1.2 MB
    float*  bqkv  = (float*)alloc((size_t)NQKV * 4);
    __bf16* qkvb  = (__bf16*)alloc((size_t)MTOK * NQKV * 2);     // 37.7 MB
    __bf16* vtb   = (__bf16*)alloc((size_t)BB * NH * HD * NSEQ * 2); // 12.6 MB
    if (off > ws_size) return;  // workspace too small -> visible failure
    __bf16* ctx = xb;  // xb dead after QKV GEMM

    k_convert_x<<<dim3(6144), dim3(256), 0, stream>>>(x, xb);
    k_bias<<<dim3(9), dim3(256), 0, stream>>>(bq, bk, bv, bqkv);
    k_transpose_w<<<dim3(24, 24, 4), dim3(256), 0, stream>>>(Wq, Wk, Wv, Wo, wtqkv, wto);
    k_gemm<__bf16><<<dim3(64, 18), dim3(256), 0, stream>>>(xb, wtqkv, bqkv, qkvb, NQKV);
    k_transpose_v<<<dim3(16, 12, 8), dim3(256), 0, stream>>>(qkvb, vtb);
    k_attn<<<dim3(16, 12, 8), dim3(256), 0, stream>>>(qkvb, vtb, ctx);
    k_gemm<float><<<dim3(64, 6), dim3(256), 0, stream>>>(ctx, wto, bo, out, DMODEL);
}